// Round 5
// baseline (94.138 us; speedup 1.0000x reference)
//
#include <hip/hip_runtime.h>

#define BATCH 16384
#define NPTS  500
#define NOBJ  30
#define EPW   2   // batch elements per wave
#define WPB   4   // waves per block
// grid = BATCH/(EPW*WPB) = 2048 blocks = 8 blocks/CU = 32 waves/CU (100% occ cap)

// raw v_sqrt_f32 (1 ULP), no IEEE denormal-fixup sequence
__device__ __forceinline__ float fsqrt(float x) {
    return __builtin_amdgcn_sqrtf(x);
}

__global__ __launch_bounds__(256) void add_loss_kernel(
    const float* __restrict__ pred_r,   // (B,4)
    const float* __restrict__ pred_t,   // (B,3)
    const float* __restrict__ gt_r,     // (B,4)
    const float* __restrict__ gt_t,     // (B,3)
    const int*   __restrict__ obj_ids,  // (B,)
    const float* __restrict__ points,   // (NOBJ, NPTS, 3)
    float* __restrict__ out)            // scalar
{
    const int wave  = threadIdx.x >> 6;
    const int lane  = threadIdx.x & 63;
    const int gwave = blockIdx.x * WPB + wave;
    const int b0    = gwave * EPW;      // 16384 = 2048*8 exactly

    float acc_pts   = 0.0f;
    float acc_trans = 0.0f;

    #pragma unroll
    for (int e = 0; e < EPW; ++e) {
        const int b = b0 + e;

        const float4 qp = ((const float4*)pred_r)[b];
        const float4 qg = ((const float4*)gt_r)[b];

        float pw=qp.x, px=qp.y, py=qp.z, pz=qp.w;
        float gw=qg.x, gx=qg.y, gy=qg.z, gz=qg.w;

        // D = Rp - Rg from unnormalized quats (paired differences)
        float d00 = 2.f*((gy*gy + gz*gz) - (py*py + pz*pz));
        float d01 = 2.f*((px*py - pw*pz) - (gx*gy - gw*gz));
        float d02 = 2.f*((px*pz + pw*py) - (gx*gz + gw*gy));
        float d10 = 2.f*((px*py + pw*pz) - (gx*gy + gw*gz));
        float d11 = 2.f*((gx*gx + gz*gz) - (px*px + pz*pz));
        float d12 = 2.f*((py*pz - pw*px) - (gy*gz - gw*gx));
        float d20 = 2.f*((px*pz - pw*py) - (gx*gz - gw*gy));
        float d21 = 2.f*((py*pz + pw*px) - (gy*gz + gw*gx));
        float d22 = 2.f*((gx*gx + gy*gy) - (px*px + py*py));

        float tdx = pred_t[3*b+0] - gt_t[3*b+0];
        float tdy = pred_t[3*b+1] - gt_t[3*b+1];
        float tdz = pred_t[3*b+2] - gt_t[3*b+2];

        const int obj = obj_ids[b];
        // object row = 1500 floats = 6000 B (16-divisible -> float4-aligned)
        const float4* __restrict__ P4 = (const float4*)(points + (size_t)obj * (NPTS*3));

        float s = 0.0f;
        // 500 points = 125 groups of 4 points (3 float4 per group).
        #pragma unroll
        for (int t = 0; t < 2; ++t) {
            const int g = t*64 + lane;
            if (t == 0 || lane < 61) {
                float4 a  = P4[3*g+0];
                float4 bq = P4[3*g+1];
                float4 c  = P4[3*g+2];
                float fx[4] = {a.x, a.w, bq.z, c.y};
                float fy[4] = {a.y, bq.x, bq.w, c.z};
                float fz[4] = {a.z, bq.y, c.x, c.w};
                #pragma unroll
                for (int j = 0; j < 4; ++j) {
                    float x = fx[j], y = fy[j], z = fz[j];
                    float vx = d00*x + d01*y + d02*z;
                    float vy = d10*x + d11*y + d12*z;
                    float vz = d20*x + d21*y + d22*z;
                    s += fsqrt(vx*vx + vy*vy + vz*vz);
                    float ax = vx + tdx, ay = vy + tdy, az = vz + tdz;
                    s += fsqrt(ax*ax + ay*ay + az*az);
                }
            }
        }

        acc_pts   += s;
        acc_trans += fsqrt(tdx*tdx + tdy*tdy + tdz*tdz);
    }

    // one butterfly per wave
    #pragma unroll
    for (int off = 32; off > 0; off >>= 1)
        acc_pts += __shfl_down(acc_pts, off, 64);

    __shared__ float red[WPB];
    if (lane == 0)
        red[wave] = acc_pts * (1.0f / NPTS) + acc_trans;
    __syncthreads();
    if (threadIdx.x == 0) {
        float sblk = red[0] + red[1] + red[2] + red[3];
        atomicAdd(out, sblk * (1.0f / BATCH));
    }
}

extern "C" void kernel_launch(void* const* d_in, const int* in_sizes, int n_in,
                              void* d_out, int out_size, void* d_ws, size_t ws_size,
                              hipStream_t stream) {
    const float* pred_r  = (const float*)d_in[0];
    const float* pred_t  = (const float*)d_in[1];
    const float* gt_r    = (const float*)d_in[2];
    const float* gt_t    = (const float*)d_in[3];
    const int*   obj_ids = (const int*)d_in[4];
    const float* points  = (const float*)d_in[5];
    float* out = (float*)d_out;

    hipMemsetAsync(out, 0, sizeof(float) * out_size, stream);

    const int blocks = BATCH / (EPW * WPB);  // 2048
    add_loss_kernel<<<blocks, 256, 0, stream>>>(
        pred_r, pred_t, gt_r, gt_t, obj_ids, points, out);
}

// Round 6
// 74.357 us; speedup vs baseline: 1.2660x; 1.2660x over previous
//
#include <hip/hip_runtime.h>

#define BATCH 16384
#define NPTS  500
#define NOBJ  30
#define EPW   4    // batch elements per wave
#define WPB   4    // waves per block
#define NBLK  (BATCH / (EPW * WPB))   // 1024 stage-1 blocks

// raw v_sqrt_f32 (1 ULP), no IEEE denormal-fixup sequence
__device__ __forceinline__ float fsqrt(float x) {
    return __builtin_amdgcn_sqrtf(x);
}

__global__ __launch_bounds__(256) void add_loss_stage1(
    const float* __restrict__ pred_r,   // (B,4)
    const float* __restrict__ pred_t,   // (B,3)
    const float* __restrict__ gt_r,     // (B,4)
    const float* __restrict__ gt_t,     // (B,3)
    const int*   __restrict__ obj_ids,  // (B,)
    const float* __restrict__ points,   // (NOBJ, NPTS, 3)
    float* __restrict__ partial)        // (NBLK,)
{
    const int wave  = threadIdx.x >> 6;
    const int lane  = threadIdx.x & 63;
    const int gwave = blockIdx.x * WPB + wave;
    const int b0    = gwave * EPW;

    float acc_pts   = 0.0f;
    float acc_trans = 0.0f;

    for (int e = 0; e < EPW; ++e) {
        const int b = b0 + e;

        const float4 qp = ((const float4*)pred_r)[b];
        const float4 qg = ((const float4*)gt_r)[b];

        float pw=qp.x, px=qp.y, py=qp.z, pz=qp.w;
        float gw=qg.x, gx=qg.y, gy=qg.z, gz=qg.w;

        // D = Rp - Rg from unnormalized quats (paired differences)
        float d00 = 2.f*((gy*gy + gz*gz) - (py*py + pz*pz));
        float d01 = 2.f*((px*py - pw*pz) - (gx*gy - gw*gz));
        float d02 = 2.f*((px*pz + pw*py) - (gx*gz + gw*gy));
        float d10 = 2.f*((px*py + pw*pz) - (gx*gy + gw*gz));
        float d11 = 2.f*((gx*gx + gz*gz) - (px*px + pz*pz));
        float d12 = 2.f*((py*pz - pw*px) - (gy*gz - gw*gx));
        float d20 = 2.f*((px*pz - pw*py) - (gx*gz - gw*gy));
        float d21 = 2.f*((py*pz + pw*px) - (gy*gz + gw*gx));
        float d22 = 2.f*((gx*gx + gy*gy) - (px*px + py*py));

        float tdx = pred_t[3*b+0] - gt_t[3*b+0];
        float tdy = pred_t[3*b+1] - gt_t[3*b+1];
        float tdz = pred_t[3*b+2] - gt_t[3*b+2];

        const int obj = obj_ids[b];
        // object row = 1500 floats = 6000 B (16-divisible -> float4-aligned)
        const float4* __restrict__ P4 = (const float4*)(points + (size_t)obj * (NPTS*3));

        float s = 0.0f;
        // 500 points = 125 groups of 4 points (3 float4 per group).
        #pragma unroll
        for (int t = 0; t < 2; ++t) {
            const int g = t*64 + lane;
            if (t == 0 || lane < 61) {
                float4 a  = P4[3*g+0];
                float4 bq = P4[3*g+1];
                float4 c  = P4[3*g+2];
                float fx[4] = {a.x, a.w, bq.z, c.y};
                float fy[4] = {a.y, bq.x, bq.w, c.z};
                float fz[4] = {a.z, bq.y, c.x, c.w};
                #pragma unroll
                for (int j = 0; j < 4; ++j) {
                    float x = fx[j], y = fy[j], z = fz[j];
                    float vx = d00*x + d01*y + d02*z;
                    float vy = d10*x + d11*y + d12*z;
                    float vz = d20*x + d21*y + d22*z;
                    s += fsqrt(vx*vx + vy*vy + vz*vz);
                    float ax = vx + tdx, ay = vy + tdy, az = vz + tdz;
                    s += fsqrt(ax*ax + ay*ay + az*az);
                }
            }
        }

        acc_pts   += s;
        acc_trans += fsqrt(tdx*tdx + tdy*tdy + tdz*tdz);
    }

    // one butterfly per wave
    #pragma unroll
    for (int off = 32; off > 0; off >>= 1)
        acc_pts += __shfl_down(acc_pts, off, 64);

    __shared__ float red[WPB];
    if (lane == 0)
        red[wave] = acc_pts * (1.0f / NPTS) + acc_trans;
    __syncthreads();
    if (threadIdx.x == 0)
        partial[blockIdx.x] = red[0] + red[1] + red[2] + red[3];  // plain store, no contention
}

__global__ __launch_bounds__(256) void add_loss_stage2(
    const float* __restrict__ partial,  // (NBLK,)
    float* __restrict__ out)            // scalar
{
    const int wave = threadIdx.x >> 6;
    const int lane = threadIdx.x & 63;

    float s = 0.0f;
    #pragma unroll
    for (int k = 0; k < NBLK / 256; ++k)
        s += partial[k * 256 + threadIdx.x];

    #pragma unroll
    for (int off = 32; off > 0; off >>= 1)
        s += __shfl_down(s, off, 64);

    __shared__ float red[4];
    if (lane == 0) red[wave] = s;
    __syncthreads();
    if (threadIdx.x == 0)
        out[0] = (red[0] + red[1] + red[2] + red[3]) * (1.0f / BATCH);
}

extern "C" void kernel_launch(void* const* d_in, const int* in_sizes, int n_in,
                              void* d_out, int out_size, void* d_ws, size_t ws_size,
                              hipStream_t stream) {
    const float* pred_r  = (const float*)d_in[0];
    const float* pred_t  = (const float*)d_in[1];
    const float* gt_r    = (const float*)d_in[2];
    const float* gt_t    = (const float*)d_in[3];
    const int*   obj_ids = (const int*)d_in[4];
    const float* points  = (const float*)d_in[5];
    float* out     = (float*)d_out;
    float* partial = (float*)d_ws;      // 1024 floats = 4 KB of scratch

    add_loss_stage1<<<NBLK, 256, 0, stream>>>(
        pred_r, pred_t, gt_r, gt_t, obj_ids, points, partial);
    add_loss_stage2<<<1, 256, 0, stream>>>(partial, out);
}

// Round 7
// 72.069 us; speedup vs baseline: 1.3062x; 1.0317x over previous
//
#include <hip/hip_runtime.h>

#define BATCH 16384
#define NPTS  500
#define NOBJ  30
#define EPW   2    // batch elements per wave
#define WPB   4    // waves per block
#define NBLK  (BATCH / (EPW * WPB))   // 2048 stage-1 blocks = 8 blocks/CU = 32 waves/CU

// raw v_sqrt_f32 (1 ULP), no IEEE denormal-fixup sequence
__device__ __forceinline__ float fsqrt(float x) {
    return __builtin_amdgcn_sqrtf(x);
}

__global__ __launch_bounds__(256) void add_loss_stage1(
    const float* __restrict__ pred_r,   // (B,4)
    const float* __restrict__ pred_t,   // (B,3)
    const float* __restrict__ gt_r,     // (B,4)
    const float* __restrict__ gt_t,     // (B,3)
    const int*   __restrict__ obj_ids,  // (B,)
    const float* __restrict__ points,   // (NOBJ, NPTS, 3)
    float* __restrict__ partial)        // (NBLK,)
{
    const int wave  = threadIdx.x >> 6;
    const int lane  = threadIdx.x & 63;
    const int gwave = blockIdx.x * WPB + wave;
    const int b0    = gwave * EPW;

    float acc_pts   = 0.0f;
    float acc_trans = 0.0f;

    #pragma unroll
    for (int e = 0; e < EPW; ++e) {
        const int b = b0 + e;

        const float4 qp = ((const float4*)pred_r)[b];
        const float4 qg = ((const float4*)gt_r)[b];

        float pw=qp.x, px=qp.y, py=qp.z, pz=qp.w;
        float gw=qg.x, gx=qg.y, gy=qg.z, gz=qg.w;

        // D = Rp - Rg from unnormalized quats (paired differences)
        float d00 = 2.f*((gy*gy + gz*gz) - (py*py + pz*pz));
        float d01 = 2.f*((px*py - pw*pz) - (gx*gy - gw*gz));
        float d02 = 2.f*((px*pz + pw*py) - (gx*gz + gw*gy));
        float d10 = 2.f*((px*py + pw*pz) - (gx*gy + gw*gz));
        float d11 = 2.f*((gx*gx + gz*gz) - (px*px + pz*pz));
        float d12 = 2.f*((py*pz - pw*px) - (gy*gz - gw*gx));
        float d20 = 2.f*((px*pz - pw*py) - (gx*gz - gw*gy));
        float d21 = 2.f*((py*pz + pw*px) - (gy*gz + gw*gx));
        float d22 = 2.f*((gx*gx + gy*gy) - (px*px + py*py));

        float tdx = pred_t[3*b+0] - gt_t[3*b+0];
        float tdy = pred_t[3*b+1] - gt_t[3*b+1];
        float tdz = pred_t[3*b+2] - gt_t[3*b+2];

        const int obj = obj_ids[b];
        // object row = 1500 floats = 6000 B (16-divisible -> float4-aligned)
        const float4* __restrict__ P4 = (const float4*)(points + (size_t)obj * (NPTS*3));

        float s = 0.0f;
        // 500 points = 125 groups of 4 points (3 float4 per group).
        #pragma unroll
        for (int t = 0; t < 2; ++t) {
            const int g = t*64 + lane;
            if (t == 0 || lane < 61) {
                float4 a  = P4[3*g+0];
                float4 bq = P4[3*g+1];
                float4 c  = P4[3*g+2];
                float fx[4] = {a.x, a.w, bq.z, c.y};
                float fy[4] = {a.y, bq.x, bq.w, c.z};
                float fz[4] = {a.z, bq.y, c.x, c.w};
                #pragma unroll
                for (int j = 0; j < 4; ++j) {
                    float x = fx[j], y = fy[j], z = fz[j];
                    float vx = d00*x + d01*y + d02*z;
                    float vy = d10*x + d11*y + d12*z;
                    float vz = d20*x + d21*y + d22*z;
                    s += fsqrt(vx*vx + vy*vy + vz*vz);
                    float ax = vx + tdx, ay = vy + tdy, az = vz + tdz;
                    s += fsqrt(ax*ax + ay*ay + az*az);
                }
            }
        }

        acc_pts   += s;
        acc_trans += fsqrt(tdx*tdx + tdy*tdy + tdz*tdz);
    }

    // one butterfly per wave
    #pragma unroll
    for (int off = 32; off > 0; off >>= 1)
        acc_pts += __shfl_down(acc_pts, off, 64);

    __shared__ float red[WPB];
    if (lane == 0)
        red[wave] = acc_pts * (1.0f / NPTS) + acc_trans;
    __syncthreads();
    if (threadIdx.x == 0)
        partial[blockIdx.x] = red[0] + red[1] + red[2] + red[3];  // plain store, no contention
}

__global__ __launch_bounds__(256) void add_loss_stage2(
    const float* __restrict__ partial,  // (NBLK,)
    float* __restrict__ out)            // scalar
{
    const int wave = threadIdx.x >> 6;
    const int lane = threadIdx.x & 63;

    float s = 0.0f;
    #pragma unroll
    for (int k = 0; k < NBLK / 256; ++k)
        s += partial[k * 256 + threadIdx.x];

    #pragma unroll
    for (int off = 32; off > 0; off >>= 1)
        s += __shfl_down(s, off, 64);

    __shared__ float red[4];
    if (lane == 0) red[wave] = s;
    __syncthreads();
    if (threadIdx.x == 0)
        out[0] = (red[0] + red[1] + red[2] + red[3]) * (1.0f / BATCH);
}

extern "C" void kernel_launch(void* const* d_in, const int* in_sizes, int n_in,
                              void* d_out, int out_size, void* d_ws, size_t ws_size,
                              hipStream_t stream) {
    const float* pred_r  = (const float*)d_in[0];
    const float* pred_t  = (const float*)d_in[1];
    const float* gt_r    = (const float*)d_in[2];
    const float* gt_t    = (const float*)d_in[3];
    const int*   obj_ids = (const int*)d_in[4];
    const float* points  = (const float*)d_in[5];
    float* out     = (float*)d_out;
    float* partial = (float*)d_ws;      // 2048 floats = 8 KB of scratch

    add_loss_stage1<<<NBLK, 256, 0, stream>>>(
        pred_r, pred_t, gt_r, gt_t, obj_ids, points, partial);
    add_loss_stage2<<<1, 256, 0, stream>>>(partial, out);
}

// Round 8
// 71.185 us; speedup vs baseline: 1.3224x; 1.0124x over previous
//
#include <hip/hip_runtime.h>

#define BATCH 16384
#define NPTS  500
#define NOBJ  30
#define EPW   2    // batch elements per wave
#define WPB   4    // waves per block
#define NBLK  (BATCH / (EPW * WPB))   // 2048 stage-1 blocks = 8 blocks/CU = 32 waves/CU

typedef float v2f __attribute__((ext_vector_type(2)));

// raw v_sqrt_f32 (1 ULP), no IEEE denormal-fixup sequence
__device__ __forceinline__ float fsqrt(float x) {
    return __builtin_amdgcn_sqrtf(x);
}

__global__ __launch_bounds__(256) void add_loss_stage1(
    const float* __restrict__ pred_r,   // (B,4)
    const float* __restrict__ pred_t,   // (B,3)
    const float* __restrict__ gt_r,     // (B,4)
    const float* __restrict__ gt_t,     // (B,3)
    const int*   __restrict__ obj_ids,  // (B,)
    const float* __restrict__ points,   // (NOBJ, NPTS, 3)
    float* __restrict__ partial)        // (NBLK,)
{
    const int wave  = threadIdx.x >> 6;
    const int lane  = threadIdx.x & 63;
    const int gwave = blockIdx.x * WPB + wave;
    const int b0    = gwave * EPW;

    float acc_pts   = 0.0f;
    float acc_trans = 0.0f;

    #pragma unroll
    for (int e = 0; e < EPW; ++e) {
        const int b = b0 + e;

        const float4 qp = ((const float4*)pred_r)[b];
        const float4 qg = ((const float4*)gt_r)[b];

        float pw=qp.x, px=qp.y, py=qp.z, pz=qp.w;
        float gw=qg.x, gx=qg.y, gy=qg.z, gz=qg.w;

        // D = Rp - Rg from unnormalized quats (paired differences)
        float d00 = 2.f*((gy*gy + gz*gz) - (py*py + pz*pz));
        float d01 = 2.f*((px*py - pw*pz) - (gx*gy - gw*gz));
        float d02 = 2.f*((px*pz + pw*py) - (gx*gz + gw*gy));
        float d10 = 2.f*((px*py + pw*pz) - (gx*gy + gw*gz));
        float d11 = 2.f*((gx*gx + gz*gz) - (px*px + pz*pz));
        float d12 = 2.f*((py*pz - pw*px) - (gy*gz - gw*gx));
        float d20 = 2.f*((px*pz - pw*py) - (gx*gz - gw*gy));
        float d21 = 2.f*((py*pz + pw*px) - (gy*gz + gw*gx));
        float d22 = 2.f*((gx*gx + gy*gy) - (px*px + py*py));

        float tdx = pred_t[3*b+0] - gt_t[3*b+0];
        float tdy = pred_t[3*b+1] - gt_t[3*b+1];
        float tdz = pred_t[3*b+2] - gt_t[3*b+2];

        const int obj = obj_ids[b];
        // object row = 1500 floats = 6000 B (16-divisible -> float4-aligned)
        const float4* __restrict__ P4 = (const float4*)(points + (size_t)obj * (NPTS*3));

        float s = 0.0f;
        // 500 points = 125 groups of 4 points (3 float4 per group).
        // Points processed as packed pairs (v2f) -> v_pk_fma_f32 / v_pk_add_f32.
        #pragma unroll
        for (int t = 0; t < 2; ++t) {
            const int g = t*64 + lane;
            if (t == 0 || lane < 61) {
                float4 a  = P4[3*g+0];
                float4 b4 = P4[3*g+1];
                float4 c  = P4[3*g+2];
                // pair 0 = points {0,1}, pair 1 = points {2,3} of the group
                v2f xs[2] = { {a.x, a.w},  {b4.z, c.y} };
                v2f ys[2] = { {a.y, b4.x}, {b4.w, c.z} };
                v2f zs[2] = { {a.z, b4.y}, {c.x, c.w} };
                #pragma unroll
                for (int j = 0; j < 2; ++j) {
                    v2f x = xs[j], y = ys[j], z = zs[j];
                    v2f vx = d00*x + d01*y + d02*z;
                    v2f vy = d10*x + d11*y + d12*z;
                    v2f vz = d20*x + d21*y + d22*z;
                    v2f r  = vx*vx + vy*vy + vz*vz;
                    s += fsqrt(r.x) + fsqrt(r.y);
                    v2f ax = vx + tdx, ay = vy + tdy, az = vz + tdz;
                    v2f r2 = ax*ax + ay*ay + az*az;
                    s += fsqrt(r2.x) + fsqrt(r2.y);
                }
            }
        }

        acc_pts   += s;
        acc_trans += fsqrt(tdx*tdx + tdy*tdy + tdz*tdz);
    }

    // one butterfly per wave
    #pragma unroll
    for (int off = 32; off > 0; off >>= 1)
        acc_pts += __shfl_down(acc_pts, off, 64);

    __shared__ float red[WPB];
    if (lane == 0)
        red[wave] = acc_pts * (1.0f / NPTS) + acc_trans;
    __syncthreads();
    if (threadIdx.x == 0)
        partial[blockIdx.x] = red[0] + red[1] + red[2] + red[3];  // plain store, no contention
}

__global__ __launch_bounds__(256) void add_loss_stage2(
    const float* __restrict__ partial,  // (NBLK,)
    float* __restrict__ out)            // scalar
{
    const int wave = threadIdx.x >> 6;
    const int lane = threadIdx.x & 63;

    float s = 0.0f;
    #pragma unroll
    for (int k = 0; k < NBLK / 256; ++k)
        s += partial[k * 256 + threadIdx.x];

    #pragma unroll
    for (int off = 32; off > 0; off >>= 1)
        s += __shfl_down(s, off, 64);

    __shared__ float red[4];
    if (lane == 0) red[wave] = s;
    __syncthreads();
    if (threadIdx.x == 0)
        out[0] = (red[0] + red[1] + red[2] + red[3]) * (1.0f / BATCH);
}

extern "C" void kernel_launch(void* const* d_in, const int* in_sizes, int n_in,
                              void* d_out, int out_size, void* d_ws, size_t ws_size,
                              hipStream_t stream) {
    const float* pred_r  = (const float*)d_in[0];
    const float* pred_t  = (const float*)d_in[1];
    const float* gt_r    = (const float*)d_in[2];
    const float* gt_t    = (const float*)d_in[3];
    const int*   obj_ids = (const int*)d_in[4];
    const float* points  = (const float*)d_in[5];
    float* out     = (float*)d_out;
    float* partial = (float*)d_ws;      // 2048 floats = 8 KB of scratch

    add_loss_stage1<<<NBLK, 256, 0, stream>>>(
        pred_r, pred_t, gt_r, gt_t, obj_ids, points, partial);
    add_loss_stage2<<<1, 256, 0, stream>>>(partial, out);
}